// Round 11
// baseline (1604.886 us; speedup 1.0000x reference)
//
#include <hip/hip_runtime.h>

#define HIDDEN 51
#define LSEQ 1000
#define UNROLL 8    // steps per group; LSEQ % UNROLL == 0

typedef float v2f __attribute__((ext_vector_type(2)));

// Branch-free tanh: tanh(v) = 1 - 2/(exp2(2*log2e*v)+1). Saturates to +/-1.
__device__ __forceinline__ float fast_tanh(float v) {
    float e = __builtin_amdgcn_exp2f(v * 2.885390081777927f);  // 2*log2(e)
    float r = __builtin_amdgcn_rcpf(e + 1.0f);
    return fmaf(-2.0f, r, 1.0f);
}

// TWO samples per wave (512 blocks x 64 lanes), instruction streams
// interleaved. Rationale from the R8/R9/R10 ledger:
//  - per-step busy (FMA issue) scales with samples, but the per-step STALL
//    (~560 cyc: LDS h turnaround, tanh/chain tails, butterfly amortization)
//    is per-step -- sharing it across 2 samples nearly halves per-sample
//    cost. Chip is latency-bound at 1 wave/SIMD, so idle SIMDs are free.
//  - Up[4][26] v2f k-pair layout + v_pk_fma (R8): the only U layout measured
//    free of the AGPR-copy tax; now SHARED by both samples (208 floats once).
//  - h broadcasts hoisted as 13+13 ds_read_b128 before the FMA blocks (R9:
//    one exposed LDS round-trip instead of 13).
//  - Butterflies ONLY at group end, 16 independent chains whose hop
//    latencies overlap (R10: a serial per-step swizzle chain = +640 cyc/step).
__global__ __launch_bounds__(64, 1) void lstm_seq_kernel(
    const float* __restrict__ x,
    const float* __restrict__ W_w,
    const float* __restrict__ W_b,
    const float* __restrict__ U_w,
    const float* __restrict__ U_b,
    const float* __restrict__ lin_w,
    const float* __restrict__ lin_b,
    float* __restrict__ out)
{
    __shared__ __attribute__((aligned(16))) float hbA[64];  // sample A h
    __shared__ __attribute__((aligned(16))) float hbB[64];  // sample B h

    const int bA   = blockIdx.x * 2;
    const int bB   = bA + 1;
    const int lane = threadIdx.x;        // 0..63
    const bool active = lane < HIDDEN;   // lanes 51..63 produce exact zeros
    const int m = active ? lane : 0;

    float ww[4], bb[4];
#pragma unroll
    for (int g = 0; g < 4; ++g) {
        const int row = m + g * HIDDEN;
        ww[g] = active ? W_w[row] : 0.f;
        bb[g] = active ? (W_b[row] + U_b[row]) : 0.f;
    }
    const float lw = active ? lin_w[m] : 0.f;
    const float lb = lin_b[0];

    // U packed over k-pairs: Up[g][j] = {U[row][2j], U[row][2j+1]}, j<26.
    // k==51 zero pad (matches hb*[51]==0). Shared by both samples.
    v2f Up[4][26];
#pragma unroll
    for (int j = 0; j < 26; ++j) {
        const int k0 = 2 * j, k1 = 2 * j + 1;
#pragma unroll
        for (int g = 0; g < 4; ++g) {
            const int row = m + g * HIDDEN;
            v2f u;
            u.x = (active && k0 < HIDDEN) ? U_w[row * HIDDEN + k0] : 0.f;
            u.y = (active && k1 < HIDDEN) ? U_w[row * HIDDEN + k1] : 0.f;
            Up[g][j] = u;
        }
    }

    float hA = 0.f, cA = 0.f, hB = 0.f, cB = 0.f;
    const float* __restrict__ xrowA = x + (long)bA * LSEQ;
    const float* __restrict__ xrowB = x + (long)bB * LSEQ;
    float* __restrict__ orowA = out + (long)bA * LSEQ;
    float* __restrict__ orowB = out + (long)bB * LSEQ;

    hbA[lane] = 0.f;
    hbB[lane] = 0.f;
    __builtin_amdgcn_wave_barrier();      // ordering insurance (no-op inst)

    for (int T = 0; T < LSEQ; T += UNROLL) {
        float xgA[UNROLL], xgB[UNROLL], rbA[UNROLL], rbB[UNROLL];
#pragma unroll
        for (int s = 0; s < UNROLL; ++s) {   // uniform loads, once per group
            xgA[s] = xrowA[T + s];
            xgB[s] = xrowB[T + s];
        }

#pragma unroll
        for (int s = 0; s < UNROLL; ++s) {
            // ---- hoisted h broadcasts for BOTH samples: 26 b128 reads ----
            float4 hvA[13], hvB[13];
#pragma unroll
            for (int q = 0; q < 13; ++q) hvA[q] = *(const float4*)&hbA[q * 4];
#pragma unroll
            for (int q = 0; q < 13; ++q) hvB[q] = *(const float4*)&hbB[q * 4];

            // ---- interleaved packed FMA blocks (A and B alternate) ----
            v2f aA0 = {0.f,0.f}, aA1 = {0.f,0.f}, aA2 = {0.f,0.f}, aA3 = {0.f,0.f};
            v2f aB0 = {0.f,0.f}, aB1 = {0.f,0.f}, aB2 = {0.f,0.f}, aB3 = {0.f,0.f};
#pragma unroll
            for (int q = 0; q < 13; ++q) {
                const v2f Alo = {hvA[q].x, hvA[q].y};
                const v2f Ahi = {hvA[q].z, hvA[q].w};
                const v2f Blo = {hvB[q].x, hvB[q].y};
                const v2f Bhi = {hvB[q].z, hvB[q].w};
                aA0 = __builtin_elementwise_fma(Alo, Up[0][2 * q], aA0);
                aA1 = __builtin_elementwise_fma(Alo, Up[1][2 * q], aA1);
                aA2 = __builtin_elementwise_fma(Alo, Up[2][2 * q], aA2);
                aA3 = __builtin_elementwise_fma(Alo, Up[3][2 * q], aA3);
                aB0 = __builtin_elementwise_fma(Blo, Up[0][2 * q], aB0);
                aB1 = __builtin_elementwise_fma(Blo, Up[1][2 * q], aB1);
                aB2 = __builtin_elementwise_fma(Blo, Up[2][2 * q], aB2);
                aB3 = __builtin_elementwise_fma(Blo, Up[3][2 * q], aB3);
                aA0 = __builtin_elementwise_fma(Ahi, Up[0][2 * q + 1], aA0);
                aA1 = __builtin_elementwise_fma(Ahi, Up[1][2 * q + 1], aA1);
                aA2 = __builtin_elementwise_fma(Ahi, Up[2][2 * q + 1], aA2);
                aA3 = __builtin_elementwise_fma(Ahi, Up[3][2 * q + 1], aA3);
                aB0 = __builtin_elementwise_fma(Bhi, Up[0][2 * q + 1], aB0);
                aB1 = __builtin_elementwise_fma(Bhi, Up[1][2 * q + 1], aB1);
                aB2 = __builtin_elementwise_fma(Bhi, Up[2][2 * q + 1], aB2);
                aB3 = __builtin_elementwise_fma(Bhi, Up[3][2 * q + 1], aB3);
            }
            const float giA = aA0.x + aA0.y + fmaf(xgA[s], ww[0], bb[0]);
            const float gfA = aA1.x + aA1.y + fmaf(xgA[s], ww[1], bb[1]);
            const float ggA = aA2.x + aA2.y + fmaf(xgA[s], ww[2], bb[2]);
            const float goA = aA3.x + aA3.y + fmaf(xgA[s], ww[3], bb[3]);
            const float giB = aB0.x + aB0.y + fmaf(xgB[s], ww[0], bb[0]);
            const float gfB = aB1.x + aB1.y + fmaf(xgB[s], ww[1], bb[1]);
            const float ggB = aB2.x + aB2.y + fmaf(xgB[s], ww[2], bb[2]);
            const float goB = aB3.x + aB3.y + fmaf(xgB[s], ww[3], bb[3]);

            // NOTE: faithful to reference -- no sigmoid on gates.
            cA = fmaf(gfA, cA, giA * ggA);
            cB = fmaf(gfB, cB, giB * ggB);
            hA = goA * fast_tanh(cA);     // B's tanh fills A's exp latency
            hB = goB * fast_tanh(cB);
            rbA[s] = hA * lw;
            rbB[s] = hB * lw;

            __builtin_amdgcn_wave_barrier();  // reads above precede writes
            hbA[lane] = hA;
            hbB[lane] = hB;
            __builtin_amdgcn_wave_barrier();  // writes precede next reads
        }

        // Group-end: 16 INDEPENDENT butterflies -- hop latencies overlap.
#pragma unroll
        for (int s = 0; s < UNROLL; ++s) {
#pragma unroll
            for (int off = 32; off > 0; off >>= 1) {
                rbA[s] += __shfl_xor(rbA[s], off, 64);
                rbB[s] += __shfl_xor(rbB[s], off, 64);
            }
        }
        if (lane == 0) {
            float4 a0 = {rbA[0] + lb, rbA[1] + lb, rbA[2] + lb, rbA[3] + lb};
            float4 a1 = {rbA[4] + lb, rbA[5] + lb, rbA[6] + lb, rbA[7] + lb};
            float4 b0 = {rbB[0] + lb, rbB[1] + lb, rbB[2] + lb, rbB[3] + lb};
            float4 b1 = {rbB[4] + lb, rbB[5] + lb, rbB[6] + lb, rbB[7] + lb};
            *(float4*)&orowA[T]     = a0;  // rows are 16B-aligned (4000 B)
            *(float4*)&orowA[T + 4] = a1;
            *(float4*)&orowB[T]     = b0;
            *(float4*)&orowB[T + 4] = b1;
        }
    }
}

extern "C" void kernel_launch(void* const* d_in, const int* in_sizes, int n_in,
                              void* d_out, int out_size, void* d_ws, size_t ws_size,
                              hipStream_t stream) {
    const float* x     = (const float*)d_in[0];
    const float* W_w   = (const float*)d_in[1];
    const float* W_b   = (const float*)d_in[2];
    const float* U_w   = (const float*)d_in[3];
    const float* U_b   = (const float*)d_in[4];
    const float* lin_w = (const float*)d_in[5];
    const float* lin_b = (const float*)d_in[6];
    // d_in[7] = future (static 0; out_size == B*LSEQ)
    float* out = (float*)d_out;

    const int B = in_sizes[0] / LSEQ;  // 1024
    lstm_seq_kernel<<<dim3(B / 2), dim3(64), 0, stream>>>(
        x, W_w, W_b, U_w, U_b, lin_w, lin_b, out);
}

// Round 12
// 1490.755 us; speedup vs baseline: 1.0766x; 1.0766x over previous
//
#include <hip/hip_runtime.h>

#define HIDDEN 51
#define LSEQ 1000
#define UNROLL 8    // steps per group; LSEQ % UNROLL == 0

typedef float v2f __attribute__((ext_vector_type(2)));

// Branch-free tanh: tanh(v) = 1 - 2/(exp2(2*log2e*v)+1). Saturates to +/-1.
__device__ __forceinline__ float fast_tanh(float v) {
    float e = __builtin_amdgcn_exp2f(v * 2.885390081777927f);  // 2*log2(e)
    float r = __builtin_amdgcn_rcpf(e + 1.0f);
    return fmaf(-2.0f, r, 1.0f);
}

// One packed gate-matvec block: gates = sum_k h_k * U[:,k] + (x*ww + bb).
// hv = 13 float4 broadcast words (52 h values, [51]=0 pad).
__device__ __forceinline__ void gate_block(
    const float4* __restrict__ hv, const v2f Up[4][26],
    float xs, const float* __restrict__ ww, const float* __restrict__ bb,
    float& gi, float& gf, float& gg, float& go)
{
    v2f a0 = {0.f, 0.f}, a1 = {0.f, 0.f}, a2 = {0.f, 0.f}, a3 = {0.f, 0.f};
#pragma unroll
    for (int q = 0; q < 13; ++q) {
        const v2f hlo = {hv[q].x, hv[q].y};
        const v2f hhi = {hv[q].z, hv[q].w};
        a0 = __builtin_elementwise_fma(hlo, Up[0][2 * q], a0);
        a1 = __builtin_elementwise_fma(hlo, Up[1][2 * q], a1);
        a2 = __builtin_elementwise_fma(hlo, Up[2][2 * q], a2);
        a3 = __builtin_elementwise_fma(hlo, Up[3][2 * q], a3);
        a0 = __builtin_elementwise_fma(hhi, Up[0][2 * q + 1], a0);
        a1 = __builtin_elementwise_fma(hhi, Up[1][2 * q + 1], a1);
        a2 = __builtin_elementwise_fma(hhi, Up[2][2 * q + 1], a2);
        a3 = __builtin_elementwise_fma(hhi, Up[3][2 * q + 1], a3);
    }
    gi = a0.x + a0.y + fmaf(xs, ww[0], bb[0]);
    gf = a1.x + a1.y + fmaf(xs, ww[1], bb[1]);
    gg = a2.x + a2.y + fmaf(xs, ww[2], bb[2]);
    go = a3.x + a3.y + fmaf(xs, ww[3], bb[3]);
}

// TWO samples per wave (512 blocks x 64 lanes), SEQUENTIAL sample blocks +
// software-pipelined h-broadcast reads. Ledger-driven:
//  - R8: v2f Up[4][26] lives in AGPRs, v_pk_fma sources them tax-free
//    (VGPR_Count=128 with 208 U floats resident). Shared by both samples.
//  - R11 spill lesson: FULLY interleaved A/B blocks keep hvA+hvB (104 regs)
//    live through the whole block -> 256 VGPR + scratch. Sequential blocks
//    cap peak liveness; cross-sample overlap still happens at the STALL
//    level: B's ~450-cyc issue stream covers A's LDS write->read latency.
//  - hv reads for step s+1 issue immediately after the h write of step s
//    (same-wave LDS pipe is in-order, so they return the new h); their
//    latency drains under the other sample's FMA block -> no exposed RT.
//  - Butterflies ONLY at group end (R10: per-step serial chain = +640 cyc),
//    16 independent chains, hop latencies overlap.
__global__ __launch_bounds__(64, 1) void lstm_seq_kernel(
    const float* __restrict__ x,
    const float* __restrict__ W_w,
    const float* __restrict__ W_b,
    const float* __restrict__ U_w,
    const float* __restrict__ U_b,
    const float* __restrict__ lin_w,
    const float* __restrict__ lin_b,
    float* __restrict__ out)
{
    __shared__ __attribute__((aligned(16))) float hbA[64];
    __shared__ __attribute__((aligned(16))) float hbB[64];

    const int bA   = blockIdx.x * 2;
    const int bB   = bA + 1;
    const int lane = threadIdx.x;        // 0..63
    const bool active = lane < HIDDEN;   // lanes 51..63 produce exact zeros
    const int m = active ? lane : 0;

    float ww[4], bb[4];
#pragma unroll
    for (int g = 0; g < 4; ++g) {
        const int row = m + g * HIDDEN;
        ww[g] = active ? W_w[row] : 0.f;
        bb[g] = active ? (W_b[row] + U_b[row]) : 0.f;
    }
    const float lw = active ? lin_w[m] : 0.f;
    const float lb = lin_b[0];

    // U packed over k-pairs; k==51 zero pad. Shared by both samples (AGPRs).
    v2f Up[4][26];
#pragma unroll
    for (int j = 0; j < 26; ++j) {
        const int k0 = 2 * j, k1 = 2 * j + 1;
#pragma unroll
        for (int g = 0; g < 4; ++g) {
            const int row = m + g * HIDDEN;
            v2f u;
            u.x = (active && k0 < HIDDEN) ? U_w[row * HIDDEN + k0] : 0.f;
            u.y = (active && k1 < HIDDEN) ? U_w[row * HIDDEN + k1] : 0.f;
            Up[g][j] = u;
        }
    }

    float hA = 0.f, cA = 0.f, hB = 0.f, cB = 0.f;
    const float* __restrict__ xrowA = x + (long)bA * LSEQ;
    const float* __restrict__ xrowB = x + (long)bB * LSEQ;
    float* __restrict__ orowA = out + (long)bA * LSEQ;
    float* __restrict__ orowB = out + (long)bB * LSEQ;

    hbA[lane] = 0.f;
    hbB[lane] = 0.f;
    __builtin_amdgcn_wave_barrier();

    // Prime the pipelined broadcast registers for step 0.
    float4 hvA[13], hvB[13];
#pragma unroll
    for (int q = 0; q < 13; ++q) hvA[q] = *(const float4*)&hbA[q * 4];
#pragma unroll
    for (int q = 0; q < 13; ++q) hvB[q] = *(const float4*)&hbB[q * 4];

    for (int T = 0; T < LSEQ; T += UNROLL) {
        float xgA[UNROLL], xgB[UNROLL], rbA[UNROLL], rbB[UNROLL];
#pragma unroll
        for (int s = 0; s < UNROLL; ++s) {   // uniform loads, once per group
            xgA[s] = xrowA[T + s];
            xgB[s] = xrowB[T + s];
        }

#pragma unroll
        for (int s = 0; s < UNROLL; ++s) {
            // ---- sample A: gates -> state update -> h write -> refill ----
            float giA, gfA, ggA, goA;
            gate_block(hvA, Up, xgA[s], ww, bb, giA, gfA, ggA, goA);
            cA = fmaf(gfA, cA, giA * ggA);           // no sigmoid (faithful)
            hA = goA * fast_tanh(cA);
            rbA[s] = hA * lw;
            __builtin_amdgcn_wave_barrier();
            hbA[lane] = hA;
#pragma unroll
            for (int q = 0; q < 13; ++q)             // next-step A broadcast;
                hvA[q] = *(const float4*)&hbA[q * 4]; // drains under B block

            // ---- sample B: same, its refill drains under butterflies ----
            // ---- / next step's A block.                              ----
            float giB, gfB, ggB, goB;
            gate_block(hvB, Up, xgB[s], ww, bb, giB, gfB, ggB, goB);
            cB = fmaf(gfB, cB, giB * ggB);
            hB = goB * fast_tanh(cB);
            rbB[s] = hB * lw;
            __builtin_amdgcn_wave_barrier();
            hbB[lane] = hB;
#pragma unroll
            for (int q = 0; q < 13; ++q)
                hvB[q] = *(const float4*)&hbB[q * 4];
        }

        // Group-end: 16 INDEPENDENT butterflies -- hop latencies overlap.
#pragma unroll
        for (int s = 0; s < UNROLL; ++s) {
#pragma unroll
            for (int off = 32; off > 0; off >>= 1) {
                rbA[s] += __shfl_xor(rbA[s], off, 64);
                rbB[s] += __shfl_xor(rbB[s], off, 64);
            }
        }
        if (lane == 0) {
            float4 a0 = {rbA[0] + lb, rbA[1] + lb, rbA[2] + lb, rbA[3] + lb};
            float4 a1 = {rbA[4] + lb, rbA[5] + lb, rbA[6] + lb, rbA[7] + lb};
            float4 b0 = {rbB[0] + lb, rbB[1] + lb, rbB[2] + lb, rbB[3] + lb};
            float4 b1 = {rbB[4] + lb, rbB[5] + lb, rbB[6] + lb, rbB[7] + lb};
            *(float4*)&orowA[T]     = a0;  // rows 16B-aligned (4000 B each)
            *(float4*)&orowA[T + 4] = a1;
            *(float4*)&orowB[T]     = b0;
            *(float4*)&orowB[T + 4] = b1;
        }
    }
}

extern "C" void kernel_launch(void* const* d_in, const int* in_sizes, int n_in,
                              void* d_out, int out_size, void* d_ws, size_t ws_size,
                              hipStream_t stream) {
    const float* x     = (const float*)d_in[0];
    const float* W_w   = (const float*)d_in[1];
    const float* W_b   = (const float*)d_in[2];
    const float* U_w   = (const float*)d_in[3];
    const float* U_b   = (const float*)d_in[4];
    const float* lin_w = (const float*)d_in[5];
    const float* lin_b = (const float*)d_in[6];
    // d_in[7] = future (static 0; out_size == B*LSEQ)
    float* out = (float*)d_out;

    const int B = in_sizes[0] / LSEQ;  // 1024
    lstm_seq_kernel<<<dim3(B / 2), dim3(64), 0, stream>>>(
        x, W_w, W_b, U_w, U_b, lin_w, lin_b, out);
}